// Round 4
// baseline (269.807 us; speedup 1.0000x reference)
//
#include <hip/hip_runtime.h>
#include <hip/hip_bf16.h>
#include <stdint.h>

// Problem constants (B,T,D,NH from reference)
#define NHh 16
#define Dm  1024
#define HD  64          // head dim = D/NH
#define Bb  4
#define Tt  4096
#define NCH 128         // chunks along T for the two-pass scans
#define CHL 32          // chunk length (NCH*CHL == Tt)

// 256x256 GEMM tile geometry
#define BM 256
#define BN 256
#define BK 64
#define NKT (Dm / BK)   // 16 K-tiles

using bf16 = __hip_bfloat16;
typedef __attribute__((ext_vector_type(8))) short short8;   // 8 bf16 in 4 VGPRs (MFMA A/B frag)
typedef __attribute__((ext_vector_type(4))) float f32x4;    // MFMA C/D frag

__device__ __forceinline__ float bf2f(bf16 v) { return __bfloat162float(v); }

// bf16 bits -> f32 (exact): bf16 is the high 16 bits of f32
__device__ __forceinline__ float b2f(unsigned short u) {
  union { unsigned int i; float f; } x; x.i = ((unsigned int)u) << 16; return x.f;
}

// fast reciprocal via v_rcp_f32 (~1 ulp; inputs are bf16-derived, tolerance is 1e-2)
__device__ __forceinline__ float frcp(float x) {
  float r; asm("v_rcp_f32 %0, %1" : "=v"(r) : "v"(x)); return r;
}

// async global->LDS, 16B per lane. LDS dest is wave-uniform base + lane*16.
__device__ __forceinline__ void gld_lds16(const void* g, void* l) {
  __builtin_amdgcn_global_load_lds(
      (const __attribute__((address_space(1))) unsigned int*)g,
      (__attribute__((address_space(3))) unsigned int*)l, 16, 0, 0);
}

// fp32 -> bf16 cast, vectorized; n divisible by 4
__global__ void cast_f32_to_bf16(const float* __restrict__ in, bf16* __restrict__ out, int n) {
  const int stride = gridDim.x * blockDim.x;
  for (int i = blockIdx.x * blockDim.x + threadIdx.x; i * 4 < n; i += stride) {
    const float4 v = *(const float4*)(in + (size_t)i * 4);
    ushort4 o;
    o.x = __bfloat16_as_ushort(__float2bfloat16(v.x));
    o.y = __bfloat16_as_ushort(__float2bfloat16(v.y));
    o.z = __bfloat16_as_ushort(__float2bfloat16(v.z));
    o.w = __bfloat16_as_ushort(__float2bfloat16(v.w));
    *(ushort4*)(out + (size_t)i * 4) = o;
  }
}

// ======== 256x256 GEMM — m201-style 4-phase-per-K-tile deep pipeline ========
// C[m][n] = sum_k A[m][k] * W[n][k]  (both K-contiguous row-major, bf16)
// 512 threads = 8 waves (2M x 4N); per-wave output 128x64 -> acc[8][4] f32x4.
// LDS = 8 slots x 16 KB.  Slab (t, j): j=0 A-kstep0, 1 B-kstep0, 2 A-kstep1,
// 3 B-kstep1; slot = (4t+j) % 8 = (t&1)*4 + j.  Slab layout: [256 rows][32 k]
// bf16 (64 B/row), chunk swizzle: 16B chunk c of row r stored at chunk
// c ^ ((r>>1)&3)  -> wave frag reads are 2-way bank aliased (free, m136).
// gld_lds writes linearly, so the GLOBAL source per lane is inverse-swizzled
// (rule #21).  Each slab = 2 gld_lds per wave (2 x 128 rows).
// Phases per K-tile (16 MFMA each; ds_reads issued BEFORE the leading
// barrier so their latency hides under barrier convergence):
//   ph1 (M0,k0): read A[M0]k0 (4) + B[all]k0 (4); stage (t+1, A-k1)
//   ph2 (M1,k0): read A[M1]k0 (4);                stage (t+1, B-k1)
//   ph3 (M0,k1): read A[M0]k1 (4) + B[all]k1 (4); stage (t+2, A-k0)
//   ph4 (M1,k1): read A[M1]k1 (4);                stage (t+2, B-k0)
// Every slab lands 6 phases before its first read.  One counted wait per
// tile: vmcnt(4) at end of ph4 retires exactly tile t+1's 4 slabs (slot
// recycling is barrier-safe: a slot's previous occupant is last read >=1
// barrier before the overwrite is issued).  vmcnt(0) only in the last 2 tiles.
// WRITE_S1: fuse per-32-row chunk sums of bf16(w)^2 into the epilogue.
template <bool OUT_BF16, bool WRITE_S1>
__global__ __launch_bounds__(512, 2) void gemm256(const bf16* __restrict__ A,
                                                  const bf16* __restrict__ W,
                                                  void* __restrict__ Cout,
                                                  float* __restrict__ S1,
                                                  int M, int N, int K) {
  extern __shared__ char smem[];   // 131072 B = 8 slots x 16384
  const int tid  = threadIdx.x;
  const int lane = tid & 63;
  const int wave = tid >> 6;       // 0..7
  // T1 XCD swizzle: 256 blocks = 8 XCDs x 32; consecutive swz share the A-panel
  const int bid = blockIdx.x;
  const int swz = (bid & 7) * 32 + (bid >> 3);
  const int bn = (swz & 3) * BN;          // N/BN = 4
  const int bm = (swz >> 2) * BM;
  const int wm = (wave >> 2) * 128;       // 2 M halves of 128 rows
  const int wn = (wave & 3) * 64;         // 4 N bands of 64 cols
  const int quad = lane >> 4;             // k-chunk of 8 within kstep
  const int l16  = lane & 15;

  // staging source (per lane): gld_lds writes slot + g*8192 + wave*1024 + lane*16
  // -> row r128 = g*128 + wave*16 + (lane>>2), stored chunk cs = lane&3;
  // logical k-chunk q = cs ^ ((r128>>1)&3)  (g*128 preserves (r>>1)&3)
  const int r128 = wave * 16 + (lane >> 2);            // 0..127
  const int q    = (lane & 3) ^ ((r128 >> 1) & 3);

  const bf16* Asrc = A + (size_t)(bm + r128) * K + q * 8;
  const bf16* Wsrc = W + (size_t)(bn + r128) * K + q * 8;

  f32x4 acc[8][4] = {};

#define SLOT(t, j) (smem + (size_t)((((t) & 1) * 4 + (j)) * 16384))
  // stage slab (t, j): j&1 selects W, j>>1 selects kstep
#define STAGE(t, j) do {                                                     \
    const bf16* s_ = ((j) & 1) ? Wsrc : Asrc;                                \
    const int ko_ = (t) * 64 + ((j) >> 1) * 32;                              \
    gld_lds16(s_ + ko_, SLOT(t, j) + wave * 1024);                           \
    gld_lds16(s_ + (size_t)128 * K + ko_, SLOT(t, j) + 8192 + wave * 1024);  \
  } while (0)
  // swizzled ds_read of one 16B frag: slab base sb, row r (0..255), chunk c
#define LD_FRAG(sb, r, c) (*(const short8*)((sb) + (size_t)(r) * 64 + ((((c) ^ (((r) >> 1) & 3))) << 4)))

  // prologue: tile0 fully + tile1's k0 slabs; wait so tile0 is landed
  STAGE(0, 0); STAGE(0, 1); STAGE(0, 2); STAGE(0, 3);
  STAGE(1, 0); STAGE(1, 1);
  asm volatile("s_waitcnt vmcnt(4)" ::: "memory");
  __builtin_amdgcn_s_barrier();
  __builtin_amdgcn_sched_barrier(0);

  short8 Af[4], Bk[4];
  for (int t = 0; t < NKT; t++) {
    const char* A0 = SLOT(t, 0);
    const char* B0 = SLOT(t, 1);
    const char* A1 = SLOT(t, 2);
    const char* B1 = SLOT(t, 3);
    const bool pf1 = (t + 1 < NKT);
    const bool pf2 = (t + 2 < NKT);

    // ---- ph1 (M0, k0) ----
#pragma unroll
    for (int nj = 0; nj < 4; nj++) Bk[nj] = LD_FRAG(B0, wn + nj * 16 + l16, quad);
#pragma unroll
    for (int mi = 0; mi < 4; mi++) Af[mi] = LD_FRAG(A0, wm + mi * 16 + l16, quad);
    if (pf1) STAGE(t + 1, 2);
    __builtin_amdgcn_sched_barrier(0);
    __builtin_amdgcn_s_barrier();
    asm volatile("s_waitcnt lgkmcnt(0)" ::: "memory");
    __builtin_amdgcn_sched_barrier(0);
    __builtin_amdgcn_s_setprio(1);
#pragma unroll
    for (int mi = 0; mi < 4; mi++)
#pragma unroll
      for (int nj = 0; nj < 4; nj++)
        acc[mi][nj] = __builtin_amdgcn_mfma_f32_16x16x32_bf16(Af[mi], Bk[nj], acc[mi][nj], 0, 0, 0);
    __builtin_amdgcn_s_setprio(0);
    __builtin_amdgcn_sched_barrier(0);
    __builtin_amdgcn_s_barrier();

    // ---- ph2 (M1, k0) ----
#pragma unroll
    for (int mi = 0; mi < 4; mi++) Af[mi] = LD_FRAG(A0, wm + 64 + mi * 16 + l16, quad);
    if (pf1) STAGE(t + 1, 3);
    __builtin_amdgcn_sched_barrier(0);
    __builtin_amdgcn_s_barrier();
    asm volatile("s_waitcnt lgkmcnt(0)" ::: "memory");
    __builtin_amdgcn_sched_barrier(0);
    __builtin_amdgcn_s_setprio(1);
#pragma unroll
    for (int mi = 0; mi < 4; mi++)
#pragma unroll
      for (int nj = 0; nj < 4; nj++)
        acc[mi + 4][nj] = __builtin_amdgcn_mfma_f32_16x16x32_bf16(Af[mi], Bk[nj], acc[mi + 4][nj], 0, 0, 0);
    __builtin_amdgcn_s_setprio(0);
    __builtin_amdgcn_sched_barrier(0);
    __builtin_amdgcn_s_barrier();

    // ---- ph3 (M0, k1) ----
#pragma unroll
    for (int nj = 0; nj < 4; nj++) Bk[nj] = LD_FRAG(B1, wn + nj * 16 + l16, quad);
#pragma unroll
    for (int mi = 0; mi < 4; mi++) Af[mi] = LD_FRAG(A1, wm + mi * 16 + l16, quad);
    if (pf2) STAGE(t + 2, 0);
    __builtin_amdgcn_sched_barrier(0);
    __builtin_amdgcn_s_barrier();
    asm volatile("s_waitcnt lgkmcnt(0)" ::: "memory");
    __builtin_amdgcn_sched_barrier(0);
    __builtin_amdgcn_s_setprio(1);
#pragma unroll
    for (int mi = 0; mi < 4; mi++)
#pragma unroll
      for (int nj = 0; nj < 4; nj++)
        acc[mi][nj] = __builtin_amdgcn_mfma_f32_16x16x32_bf16(Af[mi], Bk[nj], acc[mi][nj], 0, 0, 0);
    __builtin_amdgcn_s_setprio(0);
    __builtin_amdgcn_sched_barrier(0);
    __builtin_amdgcn_s_barrier();

    // ---- ph4 (M1, k1) ----
#pragma unroll
    for (int mi = 0; mi < 4; mi++) Af[mi] = LD_FRAG(A1, wm + 64 + mi * 16 + l16, quad);
    if (pf2) STAGE(t + 2, 1);
    __builtin_amdgcn_sched_barrier(0);
    __builtin_amdgcn_s_barrier();
    asm volatile("s_waitcnt lgkmcnt(0)" ::: "memory");
    __builtin_amdgcn_sched_barrier(0);
    __builtin_amdgcn_s_setprio(1);
#pragma unroll
    for (int mi = 0; mi < 4; mi++)
#pragma unroll
      for (int nj = 0; nj < 4; nj++)
        acc[mi + 4][nj] = __builtin_amdgcn_mfma_f32_16x16x32_bf16(Af[mi], Bk[nj], acc[mi + 4][nj], 0, 0, 0);
    __builtin_amdgcn_s_setprio(0);
    // one counted wait per tile: retire tile t+1's 4 slabs (issued >=4 phases ago)
    if (t < NKT - 2) { asm volatile("s_waitcnt vmcnt(4)" ::: "memory"); }
    else             { asm volatile("s_waitcnt vmcnt(0)" ::: "memory"); }
    __builtin_amdgcn_sched_barrier(0);
    __builtin_amdgcn_s_barrier();
  }

  // C/D layout (HW-verified): col = lane&15, row = (lane>>4)*4 + reg
#pragma unroll
  for (int nj = 0; nj < 4; nj++) {
    const int col = bn + wn + nj * 16 + l16;
    if constexpr (OUT_BF16) {
      float ss0 = 0.f, ss1 = 0.f, ss2 = 0.f, ss3 = 0.f;   // 4 chunks of 32 rows
#pragma unroll
      for (int mi = 0; mi < 8; mi++) {
        float csum = 0.f;
#pragma unroll
        for (int r = 0; r < 4; r++) {
          const int row = bm + wm + mi * 16 + quad * 4 + r;
          const bf16 hv = __float2bfloat16(acc[mi][nj][r]);
          ((bf16*)Cout)[(size_t)row * N + col] = hv;
          if constexpr (WRITE_S1) { const float fv = bf2f(hv); csum += fv * fv; }
        }
        if constexpr (WRITE_S1) {
          if (mi < 2) ss0 += csum;
          else if (mi < 4) ss1 += csum;
          else if (mi < 6) ss2 += csum;
          else ss3 += csum;
        }
      }
      if constexpr (WRITE_S1) {
        ss0 += __shfl_xor(ss0, 16, 64); ss0 += __shfl_xor(ss0, 32, 64);
        ss1 += __shfl_xor(ss1, 16, 64); ss1 += __shfl_xor(ss1, 32, 64);
        ss2 += __shfl_xor(ss2, 16, 64); ss2 += __shfl_xor(ss2, 32, 64);
        ss3 += __shfl_xor(ss3, 16, 64); ss3 += __shfl_xor(ss3, 32, 64);
        if (quad == 0) {
          const int h = col >> 6, d = col & 63;
          const int r0 = bm + wm;                    // first row of this wave's 128-row band
          const int b  = r0 >> 12;                   // / Tt
          const int c0 = (r0 & (Tt - 1)) >> 5;       // / CHL (=32)
          float* s1p = S1 + (((size_t)(b * NHh + h) * NCH) + c0) * HD + d;
          s1p[0]      = ss0;
          s1p[HD]     = ss1;
          s1p[2 * HD] = ss2;
          s1p[3 * HD] = ss3;
        }
      }
    } else {
#pragma unroll
      for (int mi = 0; mi < 8; mi++)
#pragma unroll
        for (int r = 0; r < 4; r++) {
          const int row = bm + wm + mi * 16 + quad * 4 + r;
          ((float*)Cout)[(size_t)row * N + col] = acc[mi][nj][r];
        }
    }
  }
#undef SLOT
#undef STAGE
#undef LD_FRAG
}

// penalty[b,t] = (phi[b,t] - cumsum(phi)[b,t]/(t+1))^2 ; 1024-thread block scan per batch
__global__ __launch_bounds__(1024) void phi_penalty_kernel(const float* __restrict__ phi,
                                                           float* __restrict__ penalty) {
  const int b = blockIdx.x;
  const int tid = threadIdx.x;            // 1024
  const int lane = tid & 63, wid = tid >> 6;   // 16 waves
  __shared__ float wsum[16];
  __shared__ float carry_s;
  if (tid == 0) carry_s = 0.f;
  __syncthreads();
  for (int r = 0; r < Tt / 1024; r++) {
    const int t = r * 1024 + tid;
    const float v = phi[b * Tt + t];
    float incl = v;
#pragma unroll
    for (int off = 1; off < 64; off <<= 1) {
      float n = __shfl_up(incl, off, 64);
      if (lane >= off) incl += n;
    }
    if (lane == 63) wsum[wid] = incl;
    __syncthreads();
    float woff = carry_s;
    for (int wpre = 0; wpre < wid; wpre++) woff += wsum[wpre];
    const float csum = woff + incl;
    const float mean = csum / (float)(t + 1);
    const float dphi = v - mean;
    penalty[b * Tt + t] = dphi * dphi;
    __syncthreads();
    if (tid == 0) {
      float s = 0.f;
      for (int w = 0; w < 16; w++) s += wsum[w];
      carry_s += s;
    }
    __syncthreads();
  }
}

// in-place exclusive prefix over chunks, per (b,h,d) — LDS-tile version.
__global__ __launch_bounds__(64) void prefix_vec(float* __restrict__ S) {
  __shared__ float tile[NCH * HD];          // 32 KB
  const int bh = blockIdx.x, tid = threadIdx.x;
  float* p = S + (size_t)bh * NCH * HD;
  const float4* src = (const float4*)p;
  float4* dst = (float4*)tile;
#pragma unroll 4
  for (int k = 0; k < (NCH * HD / 4) / 64; k++) dst[k * 64 + tid] = src[k * 64 + tid];
  __syncthreads();
  float run = 0.f;
  for (int c = 0; c < NCH; c++) {
    const float v = tile[c * HD + tid];
    tile[c * HD + tid] = run;
    run += v;
  }
  __syncthreads();
  float4* out = (float4*)p;
#pragma unroll 4
  for (int k = 0; k < (NCH * HD / 4) / 64; k++) out[k * 64 + tid] = dst[k * 64 + tid];
}

// fused exclusive prefix for dots: S2 (LDS-tile column scan) + SA (wave shfl scan, 2/lane)
__global__ __launch_bounds__(64) void prefix_dots(float* __restrict__ S2, float* __restrict__ SA) {
  __shared__ float tile[NCH * HD];          // 32 KB
  const int bh = blockIdx.x, tid = threadIdx.x;
  float* q = SA + (size_t)bh * NCH;
  const float v0 = q[tid], v1 = q[64 + tid];
  float i0 = v0;
#pragma unroll
  for (int off = 1; off < 64; off <<= 1) {
    const float n = __shfl_up(i0, off, 64);
    if (tid >= off) i0 += n;
  }
  const float tot0 = __shfl(i0, 63, 64);
  float i1 = v1;
#pragma unroll
  for (int off = 1; off < 64; off <<= 1) {
    const float n = __shfl_up(i1, off, 64);
    if (tid >= off) i1 += n;
  }
  i1 += tot0;
  q[tid] = i0 - v0;
  q[64 + tid] = i1 - v1;
  float* p = S2 + (size_t)bh * NCH * HD;
  const float4* src = (const float4*)p;
  float4* dst = (float4*)tile;
#pragma unroll 4
  for (int k = 0; k < (NCH * HD / 4) / 64; k++) dst[k * 64 + tid] = src[k * 64 + tid];
  __syncthreads();
  float run = 0.f;
  for (int c = 0; c < NCH; c++) {
    const float v = tile[c * HD + tid];
    tile[c * HD + tid] = run;
    run += v;
  }
  __syncthreads();
  float4* out = (float4*)p;
#pragma unroll 4
  for (int k = 0; k < (NCH * HD / 4) / 64; k++) out[k * 64 + tid] = dst[k * 64 + tid];
}

// ===== fused middle: tssa (pass 1) -> softmax over heads -> dots sums (pass 2)
__global__ __launch_bounds__(256) void mid_fused(const bf16* __restrict__ w,
                                                 const float* __restrict__ S1ex,
                                                 const float* __restrict__ temp,
                                                 const float* __restrict__ gamma,
                                                 const float* __restrict__ penalty,
                                                 float* __restrict__ alpha_f,
                                                 float* __restrict__ S2,
                                                 float* __restrict__ SA) {
  const int c = blockIdx.x, b = blockIdx.y;
  const int tid = threadIdx.x, h = tid >> 4, l = tid & 15;
  __shared__ float sm_t[CHL][NHh + 1];
  __shared__ float sm_a[CHL][NHh + 1];
  __shared__ float sm_g[NHh], sm_tv[NHh];
  if (tid < NHh) { sm_g[tid] = gamma[tid]; sm_tv[tid] = temp[tid]; }
  __syncthreads();

  const bf16* wp = w + ((size_t)(b * Tt + c * CHL)) * Dm + h * HD + l * 4;
  const float4 ex = *(const float4*)&S1ex[(((size_t)(b * NHh + h) * NCH) + c) * HD + l * 4];
  float a0 = ex.x, a1 = ex.y, a2 = ex.z, a3 = ex.w;
  const float tv = sm_tv[h];
#pragma unroll 8
  for (int i = 0; i < CHL; i++) {
    const ushort4 v = *(const ushort4*)(wp + (size_t)i * Dm);
    const float f0 = b2f(v.x), f1 = b2f(v.y), f2 = b2f(v.z), f3 = b2f(v.w);
    const float s0 = f0 * f0, s1 = f1 * f1, s2 = f2 * f2, s3 = f3 * f3;
    a0 += s0; a1 += s1; a2 += s2; a3 += s3;
    float val = s0 * frcp(fmaxf(a0, 1e-12f)) + s1 * frcp(fmaxf(a1, 1e-12f))
              + s2 * frcp(fmaxf(a2, 1e-12f)) + s3 * frcp(fmaxf(a3, 1e-12f));
    val += __shfl_xor(val, 1, 64);
    val += __shfl_xor(val, 2, 64);
    val += __shfl_xor(val, 4, 64);
    val += __shfl_xor(val, 8, 64);
    if (l == 0) sm_t[i][h] = tv * val;
  }
  __syncthreads();

  if (tid < CHL) {
    const int t = tid;
    const float pen = penalty[(size_t)b * Tt + c * CHL + t];
    float sc[NHh];
    float mx = -1e30f;
#pragma unroll
    for (int hh = 0; hh < NHh; hh++) {
      sc[hh] = sm_t[t][hh] - sm_g[hh] * pen;
      mx = fmaxf(mx, sc[hh]);
    }
    float sum = 0.f;
#pragma unroll
    for (int hh = 0; hh < NHh; hh++) { const float e = __expf(sc[hh] - mx); sc[hh] = e; sum += e; }
    const float inv = 1.f / sum;
#pragma unroll
    for (int hh = 0; hh < NHh; hh++) sm_a[t][hh] = sc[hh] * inv;
  }
  __syncthreads();

#pragma unroll
  for (int k2 = 0; k2 < CHL / 16; k2++) {
    const int t = k2 * 16 + l;
    alpha_f[((size_t)(b * NHh + h)) * Tt + c * CHL + t] = sm_a[t][h];
  }

  float d0 = 0.f, d1 = 0.f, d2 = 0.f, d3 = 0.f, sa = 0.f;
#pragma unroll 8
  for (int i = 0; i < CHL; i++) {
    const float a = sm_a[i][h];
    const ushort4 v = *(const ushort4*)(wp + (size_t)i * Dm);
    const float f0 = b2f(v.x), f1 = b2f(v.y), f2 = b2f(v.z), f3 = b2f(v.w);
    d0 += f0 * f0 * a; d1 += f1 * f1 * a; d2 += f2 * f2 * a; d3 += f3 * f3 * a;
    sa += a;
  }
  float4 o; o.x = d0; o.y = d1; o.z = d2; o.w = d3;
  *(float4*)&S2[(((size_t)(b * NHh + h) * NCH) + c) * HD + l * 4] = o;
  if (l == 0) SA[(size_t)(b * NHh + h) * NCH + c] = sa;
}

// y'[b,t,h*64+d] = -w * alpha * min(1/(1+dots), 1e4), bf16 (vectorized 4 d/lane)
__global__ __launch_bounds__(64) void y_phase3(const bf16* __restrict__ w,
                                               const float* __restrict__ alpha_f,
                                               const float* __restrict__ S2ex,
                                               const float* __restrict__ SAex,
                                               bf16* __restrict__ yprime) {
  const int g = threadIdx.x >> 4, l = threadIdx.x & 15;
  const int c = blockIdx.x * 4 + g, h = blockIdx.y, b = blockIdx.z;
  const float4 ex = *(const float4*)&S2ex[(((size_t)(b * NHh + h) * NCH) + c) * HD + l * 4];
  float a0 = ex.x, a1 = ex.y, a2 = ex.z, a3 = ex.w;
  float acca = SAex[(size_t)(b * NHh + h) * NCH + c];
  const bf16* wp = w + ((size_t)(b * Tt + c * CHL)) * Dm + h * HD + l * 4;
  const float* ap = alpha_f + (size_t)(b * NHh + h) * Tt + c * CHL;
  bf16* yp = yprime + ((size_t)(b * Tt + c * CHL)) * Dm + h * HD + l * 4;
#pragma unroll 8
  for (int i = 0; i < CHL; i++) {
    const float a = ap[i];
    const ushort4 v = *(const ushort4*)(wp + (size_t)i * Dm);
    const float f0 = b2f(v.x), f1 = b2f(v.y), f2 = b2f(v.z), f3 = b2f(v.w);
    a0 += f0 * f0 * a; a1 += f1 * f1 * a; a2 += f2 * f2 * a; a3 += f3 * f3 * a;
    acca += a;
    const float rinv = frcp(acca + 1e-8f);
    const float at0 = fminf(frcp(1.f + a0 * rinv), 10000.f);
    const float at1 = fminf(frcp(1.f + a1 * rinv), 10000.f);
    const float at2 = fminf(frcp(1.f + a2 * rinv), 10000.f);
    const float at3 = fminf(frcp(1.f + a3 * rinv), 10000.f);
    ushort4 o;
    o.x = __bfloat16_as_ushort(__float2bfloat16(-f0 * a * at0));
    o.y = __bfloat16_as_ushort(__float2bfloat16(-f1 * a * at1));
    o.z = __bfloat16_as_ushort(__float2bfloat16(-f2 * a * at2));
    o.w = __bfloat16_as_ushort(__float2bfloat16(-f3 * a * at3));
    *(ushort4*)(yp + (size_t)i * Dm) = o;
  }
}

extern "C" void kernel_launch(void* const* d_in, const int* in_sizes, int n_in,
                              void* d_out, int out_size, void* d_ws, size_t ws_size,
                              hipStream_t stream) {
  const float* x     = (const float*)d_in[0];
  const float* phi   = (const float*)d_in[1];
  const float* Wattn = (const float*)d_in[2];
  const float* Wproj = (const float*)d_in[3];
  const float* gamma = (const float*)d_in[4];
  const float* temp  = (const float*)d_in[5];

  float* y_out    = (float*)d_out;                          // (B,T,D) fp32
  float* alpha_f  = y_out + (size_t)Bb * Tt * Dm;           // (B,NH,T) fp32

  char* ws = (char*)d_ws;
  bf16*  x_bf   = (bf16*)ws;  ws += (size_t)Bb * Tt * Dm * 2;         // 32 MB
  bf16*  Wa_bf  = (bf16*)ws;  ws += (size_t)Dm * Dm * 2;              // 2 MB
  bf16*  Wp_bf  = (bf16*)ws;  ws += (size_t)Dm * Dm * 2;              // 2 MB
  bf16*  w_bf   = (bf16*)ws;  ws += (size_t)Bb * Tt * Dm * 2;         // 32 MB
  float* pen    = (float*)ws; ws += (size_t)Bb * Tt * 4;              // 64 KB
  float* S1     = (float*)ws; ws += (size_t)Bb * NHh * NCH * HD * 4;  // 2 MB
  float* S2     = (float*)ws; ws += (size_t)Bb * NHh * NCH * HD * 4;  // 2 MB
  float* SA     = (float*)ws; ws += (size_t)Bb * NHh * NCH * 4;       // 32 KB
  bf16*  yprime = x_bf;  // alias: x_bf is dead after GEMM1

  static int attr_done = 0;
  if (!attr_done) {
    hipFuncSetAttribute((const void*)gemm256<true, true>,
                        hipFuncAttributeMaxDynamicSharedMemorySize, 131072);
    hipFuncSetAttribute((const void*)gemm256<false, false>,
                        hipFuncAttributeMaxDynamicSharedMemorySize, 131072);
    attr_done = 1;
  }

  const int M = Bb * Tt, N = Dm, K = Dm;
  dim3 gg((M / BM) * (N / BN)), gb(512);
  dim3 g3(NCH / 4, NHh, Bb), b64(64);

  cast_f32_to_bf16<<<dim3(1024), dim3(256), 0, stream>>>(x, x_bf, Bb * Tt * Dm);
  cast_f32_to_bf16<<<dim3(256), dim3(256), 0, stream>>>(Wattn, Wa_bf, Dm * Dm);
  cast_f32_to_bf16<<<dim3(256), dim3(256), 0, stream>>>(Wproj, Wp_bf, Dm * Dm);

  gemm256<true, true><<<gg, gb, 131072, stream>>>(x_bf, Wa_bf, (void*)w_bf, S1, M, N, K);
  phi_penalty_kernel<<<dim3(Bb), dim3(1024), 0, stream>>>(phi, pen);
  prefix_vec<<<dim3(Bb * NHh), b64, 0, stream>>>(S1);
  mid_fused<<<dim3(NCH, Bb), dim3(256), 0, stream>>>(w_bf, S1, temp, gamma, pen,
                                                     alpha_f, S2, SA);
  prefix_dots<<<dim3(Bb * NHh), b64, 0, stream>>>(S2, SA);
  y_phase3<<<g3, b64, 0, stream>>>(w_bf, alpha_f, S2, SA, yprime);
  gemm256<false, false><<<gg, gb, 131072, stream>>>(yprime, Wp_bf, (void*)y_out, nullptr, M, N, K);
}

// Round 5
// 268.332 us; speedup vs baseline: 1.0055x; 1.0055x over previous
//
#include <hip/hip_runtime.h>
#include <hip/hip_bf16.h>
#include <stdint.h>

// Problem constants (B,T,D,NH from reference)
#define NHh 16
#define Dm  1024
#define HD  64          // head dim = D/NH
#define Bb  4
#define Tt  4096
#define NCH 128         // chunks along T for the two-pass scans
#define CHL 32          // chunk length (NCH*CHL == Tt)

// 256x256 GEMM tile geometry
#define BM 256
#define BN 256
#define BK 64
#define NKT (Dm / BK)   // 16 K-tiles

using bf16 = __hip_bfloat16;
typedef __attribute__((ext_vector_type(8))) short short8;   // 8 bf16 in 4 VGPRs (MFMA A/B frag)
typedef __attribute__((ext_vector_type(4))) float f32x4;    // MFMA C/D frag

__device__ __forceinline__ float bf2f(bf16 v) { return __bfloat162float(v); }

// bf16 bits -> f32 (exact): bf16 is the high 16 bits of f32
__device__ __forceinline__ float b2f(unsigned short u) {
  union { unsigned int i; float f; } x; x.i = ((unsigned int)u) << 16; return x.f;
}

// fast reciprocal via v_rcp_f32 (~1 ulp; inputs are bf16-derived, tolerance is 1e-2)
__device__ __forceinline__ float frcp(float x) {
  float r; asm("v_rcp_f32 %0, %1" : "=v"(r) : "v"(x)); return r;
}

// async global->LDS, 16B per lane. LDS dest is wave-uniform base + lane*16.
__device__ __forceinline__ void gld_lds16(const void* g, void* l) {
  __builtin_amdgcn_global_load_lds(
      (const __attribute__((address_space(1))) unsigned int*)g,
      (__attribute__((address_space(3))) unsigned int*)l, 16, 0, 0);
}

// ============== 256x256 GEMM, counted-vmcnt 2-phase pipeline (round-2 best) ==
// C[m][n] = sum_k A[m][k] * W[n][k]  (both K-contiguous row-major, bf16)
// 512 threads = 8 waves as 4M x 2N; per-wave output 64x128 -> acc[4][8].
// Phases split by N-half so read-sets partition by staged slab:
//   P1 reads: A rows all + B rows {0-63, 128-191}
//   P2 reads: B rows {64-127, 192-255}
// Staging of tile t+1: P1 issues 6 slabs (A0-3, B0, B2); P2 issues 2 (B1, B3).
// Counted waits: end-P1 vmcnt(6), end-P2 vmcnt(2); vmcnt(0) only at the end.
// LDS XOR swizzle (both-sides, rule #21): logical [256][64] bf16 rows of
// 128 B; byte P stored at P ^ ((row&7)<<4); gld_lds dest linear so the global
// source per lane is inverse-swizzled; reads apply the same XOR.
// WRITE_S1: fuse per-32-row chunk sums of bf16(w)^2 into the epilogue.
template <bool OUT_BF16, bool WRITE_S1>
__global__ __launch_bounds__(512, 2) void gemm256(const bf16* __restrict__ A,
                                                  const bf16* __restrict__ W,
                                                  void* __restrict__ Cout,
                                                  float* __restrict__ S1,
                                                  int M, int N, int K) {
  extern __shared__ char smem[];   // 131072 B: [buf][A 32K | B 32K]
  const int tid  = threadIdx.x;
  const int lane = tid & 63;
  const int wave = tid >> 6;       // 0..7
  // T1 XCD swizzle: 256 blocks = 8 XCDs x 32; consecutive swz share the A-panel
  const int bid = blockIdx.x;
  const int swz = (bid & 7) * 32 + (bid >> 3);
  const int bn = (swz & 3) * BN;          // N/BN = 4
  const int bm = (swz >> 2) * BM;
  const int wm = (wave >> 1) * 64;        // 4 M bands of 64 rows
  const int wn = (wave & 1) * 128;        // 2 N halves of 128 cols
  const int quad = lane >> 4;
  const int l16  = lane & 15;

  // staging source (per lane, per slab n): inverse-swizzled global address
  const int srow = wave * 8 + (lane >> 3);               // + n*64
  const int scol = (((lane & 7) ^ (lane >> 3)) << 3);    // elements

  const bf16* Abase = A + (size_t)(bm + srow) * K + scol;
  const bf16* Wbase = W + (size_t)(bn + srow) * K + scol;

  f32x4 acc[4][8] = {};

#define SLAB_A(buf, n) (smem + (buf) * 65536 + (n) * 8192 + wave * 1024)
#define SLAB_B(buf, n) (smem + (buf) * 65536 + 32768 + (n) * 8192 + wave * 1024)
#define STAGE_A(buf, n, k0) gld_lds16(Abase + (size_t)(n) * 64 * K + (k0), SLAB_A(buf, n))
#define STAGE_B(buf, n, k0) gld_lds16(Wbase + (size_t)(n) * 64 * K + (k0), SLAB_B(buf, n))
  // swizzled ds_read of one 16B fragment (r = row 0..255, s = 16B slot 0..7)
#define LD_FRAG(base, r, s) (*(const short8*)((base) + (size_t)(r) * 128 + ((((s) ^ ((r) & 7))) << 4)))

  // prologue: stage tile 0 fully into buf 0
  STAGE_A(0, 0, 0); STAGE_A(0, 1, 0); STAGE_A(0, 2, 0); STAGE_A(0, 3, 0);
  STAGE_B(0, 0, 0); STAGE_B(0, 1, 0); STAGE_B(0, 2, 0); STAGE_B(0, 3, 0);
  asm volatile("s_waitcnt vmcnt(0)" ::: "memory");
  __builtin_amdgcn_s_barrier();
  __builtin_amdgcn_sched_barrier(0);

  short8 af[4][2], bfv[4][2];
  for (int t = 0; t < NKT; t++) {
    const int buf = t & 1;
    const char* aL = smem + buf * 65536;
    const char* bL = aL + 32768;
    const int k0n = (t + 1) * BK;
    const bool pf = (t + 1 < NKT);

    // ---- P1: stage 6 slabs (t+1), read A-all + B lower-halves, MFMA nj 0-3
    if (pf) {
      STAGE_A(buf ^ 1, 0, k0n); STAGE_A(buf ^ 1, 1, k0n);
      STAGE_A(buf ^ 1, 2, k0n); STAGE_A(buf ^ 1, 3, k0n);
      STAGE_B(buf ^ 1, 0, k0n); STAGE_B(buf ^ 1, 2, k0n);
    }
#pragma unroll
    for (int mi = 0; mi < 4; mi++) {
      const int r = wm + mi * 16 + l16;
      af[mi][0] = LD_FRAG(aL, r, quad);
      af[mi][1] = LD_FRAG(aL, r, quad + 4);
    }
#pragma unroll
    for (int nj = 0; nj < 4; nj++) {
      const int r = wn + nj * 16 + l16;
      bfv[nj][0] = LD_FRAG(bL, r, quad);
      bfv[nj][1] = LD_FRAG(bL, r, quad + 4);
    }
    __builtin_amdgcn_s_setprio(1);
#pragma unroll
    for (int mi = 0; mi < 4; mi++)
#pragma unroll
      for (int nj = 0; nj < 4; nj++) {
        acc[mi][nj] = __builtin_amdgcn_mfma_f32_16x16x32_bf16(af[mi][0], bfv[nj][0], acc[mi][nj], 0, 0, 0);
        acc[mi][nj] = __builtin_amdgcn_mfma_f32_16x16x32_bf16(af[mi][1], bfv[nj][1], acc[mi][nj], 0, 0, 0);
      }
    __builtin_amdgcn_s_setprio(0);
    if (pf) { asm volatile("s_waitcnt vmcnt(6)" ::: "memory"); }
    else    { asm volatile("s_waitcnt vmcnt(0)" ::: "memory"); }
    __builtin_amdgcn_s_barrier();
    __builtin_amdgcn_sched_barrier(0);

    // ---- P2: stage 2 slabs (t+1), read B upper-halves, MFMA nj 4-7
    if (pf) { STAGE_B(buf ^ 1, 1, k0n); STAGE_B(buf ^ 1, 3, k0n); }
#pragma unroll
    for (int nj = 0; nj < 4; nj++) {
      const int r = wn + 64 + nj * 16 + l16;
      bfv[nj][0] = LD_FRAG(bL, r, quad);
      bfv[nj][1] = LD_FRAG(bL, r, quad + 4);
    }
    __builtin_amdgcn_s_setprio(1);
#pragma unroll
    for (int mi = 0; mi < 4; mi++)
#pragma unroll
      for (int nj = 0; nj < 4; nj++) {
        acc[mi][nj + 4] = __builtin_amdgcn_mfma_f32_16x16x32_bf16(af[mi][0], bfv[nj][0], acc[mi][nj + 4], 0, 0, 0);
        acc[mi][nj + 4] = __builtin_amdgcn_mfma_f32_16x16x32_bf16(af[mi][1], bfv[nj][1], acc[mi][nj + 4], 0, 0, 0);
      }
    __builtin_amdgcn_s_setprio(0);
    asm volatile("s_waitcnt vmcnt(2)" ::: "memory");
    __builtin_amdgcn_s_barrier();
    __builtin_amdgcn_sched_barrier(0);
  }

  // C/D layout (HW-verified): col = lane&15, row = (lane>>4)*4 + reg
#pragma unroll
  for (int nj = 0; nj < 8; nj++) {
    const int col = bn + wn + nj * 16 + l16;
    if constexpr (OUT_BF16) {
      float ss0 = 0.f, ss1 = 0.f;   // two 32-row chunks of this wave's 64-row band
#pragma unroll
      for (int mi = 0; mi < 4; mi++) {
        float csum = 0.f;
#pragma unroll
        for (int r = 0; r < 4; r++) {
          const int row = bm + wm + mi * 16 + quad * 4 + r;
          const bf16 hv = __float2bfloat16(acc[mi][nj][r]);
          ((bf16*)Cout)[(size_t)row * N + col] = hv;
          if constexpr (WRITE_S1) { const float fv = bf2f(hv); csum += fv * fv; }
        }
        if constexpr (WRITE_S1) { if (mi < 2) ss0 += csum; else ss1 += csum; }
      }
      if constexpr (WRITE_S1) {
        ss0 += __shfl_xor(ss0, 16, 64); ss0 += __shfl_xor(ss0, 32, 64);
        ss1 += __shfl_xor(ss1, 16, 64); ss1 += __shfl_xor(ss1, 32, 64);
        if (quad == 0) {
          const int h = col >> 6, d = col & 63;
          const int r0 = bm + wm;                    // first row of this wave's band
          const int b  = r0 >> 12;                   // / Tt
          const int c0 = (r0 & (Tt - 1)) >> 5;       // / CHL (=32)
          float* s1p = S1 + (((size_t)(b * NHh + h) * NCH) + c0) * HD + d;
          s1p[0]  = ss0;
          s1p[HD] = ss1;
        }
      }
    } else {
#pragma unroll
      for (int mi = 0; mi < 4; mi++)
#pragma unroll
        for (int r = 0; r < 4; r++) {
          const int row = bm + wm + mi * 16 + quad * 4 + r;
          ((float*)Cout)[(size_t)row * N + col] = acc[mi][nj][r];
        }
    }
  }
#undef SLAB_A
#undef SLAB_B
#undef STAGE_A
#undef STAGE_B
#undef LD_FRAG
}

// ===== prep: fused {cast x, cast W_attn, cast W_proj, phi->penalty} ==========
// blocks [0,1024)  : cast x (grid-stride)
// blocks [1024,1280): cast W_attn
// blocks [1280,1536): cast W_proj
// blocks [1536,1540): penalty[b,t] = (phi - cumsum(phi)/(t+1))^2, block scan
__global__ __launch_bounds__(256) void prep(const float* __restrict__ x,
                                            const float* __restrict__ Wa,
                                            const float* __restrict__ Wp,
                                            const float* __restrict__ phi,
                                            bf16* __restrict__ x_bf,
                                            bf16* __restrict__ Wa_bf,
                                            bf16* __restrict__ Wp_bf,
                                            float* __restrict__ penalty) {
  const int bid = blockIdx.x;
  if (bid < 1536) {
    const float* in;
    bf16* out;
    int n, nblk, b0;
    if (bid < 1024)      { in = x;  out = x_bf;  n = Bb * Tt * Dm; nblk = 1024; b0 = 0; }
    else if (bid < 1280) { in = Wa; out = Wa_bf; n = Dm * Dm;      nblk = 256;  b0 = 1024; }
    else                 { in = Wp; out = Wp_bf; n = Dm * Dm;      nblk = 256;  b0 = 1280; }
    const int stride = nblk * 256;
    for (int i = (bid - b0) * 256 + threadIdx.x; i * 4 < n; i += stride) {
      const float4 v = *(const float4*)(in + (size_t)i * 4);
      ushort4 o;
      o.x = __bfloat16_as_ushort(__float2bfloat16(v.x));
      o.y = __bfloat16_as_ushort(__float2bfloat16(v.y));
      o.z = __bfloat16_as_ushort(__float2bfloat16(v.z));
      o.w = __bfloat16_as_ushort(__float2bfloat16(v.w));
      *(ushort4*)(out + (size_t)i * 4) = o;
    }
  } else {
    const int b = bid - 1536;
    const int tid = threadIdx.x;            // 256
    const int lane = tid & 63, wid = tid >> 6;
    __shared__ float wsum[4];
    __shared__ float carry_s;
    if (tid == 0) carry_s = 0.f;
    __syncthreads();
    for (int r = 0; r < Tt / 256; r++) {
      const int t = r * 256 + tid;
      const float v = phi[b * Tt + t];
      float incl = v;
#pragma unroll
      for (int off = 1; off < 64; off <<= 1) {
        float nn = __shfl_up(incl, off, 64);
        if (lane >= off) incl += nn;
      }
      if (lane == 63) wsum[wid] = incl;
      __syncthreads();
      float woff = carry_s;
      for (int wpre = 0; wpre < wid; wpre++) woff += wsum[wpre];
      const float csum = woff + incl;
      const float mean = csum / (float)(t + 1);
      const float dphi = v - mean;
      penalty[b * Tt + t] = dphi * dphi;
      __syncthreads();
      if (tid == 0) carry_s += wsum[0] + wsum[1] + wsum[2] + wsum[3];
      __syncthreads();
    }
  }
}

// ===== fused middle: inline S1 prefix -> tssa -> softmax(heads) -> dots sums =
// One block per (chunk, batch): 256 threads = 16 heads x 16 lanes.
// S1 holds RAW per-chunk sums (from gemm1 epilogue); each thread computes its
// own exclusive base by summing chunks < c (independent L2 loads, ILP-unrolled).
__global__ __launch_bounds__(256) void mid_fused(const bf16* __restrict__ w,
                                                 const float* __restrict__ S1,
                                                 const float* __restrict__ temp,
                                                 const float* __restrict__ gamma,
                                                 const float* __restrict__ penalty,
                                                 float* __restrict__ alpha_f,
                                                 float* __restrict__ S2,
                                                 float* __restrict__ SA) {
  const int c = blockIdx.x, b = blockIdx.y;
  const int tid = threadIdx.x, h = tid >> 4, l = tid & 15;
  __shared__ float sm_t[CHL][NHh + 1];
  __shared__ float sm_a[CHL][NHh + 1];
  __shared__ float sm_g[NHh], sm_tv[NHh];
  if (tid < NHh) { sm_g[tid] = gamma[tid]; sm_tv[tid] = temp[tid]; }

  // inline exclusive prefix of S1 over chunks < c (stride HD floats = 16 float4)
  const float4* p4 = (const float4*)(S1 + (((size_t)(b * NHh + h) * NCH)) * HD + l * 4);
  float bx = 0.f, by = 0.f, bz = 0.f, bw = 0.f;
  float cx = 0.f, cy = 0.f, cz = 0.f, cw = 0.f;
  int cc = 0;
  for (; cc + 2 <= c; cc += 2) {
    const float4 v0 = p4[(size_t)cc * 16];
    const float4 v1 = p4[(size_t)(cc + 1) * 16];
    bx += v0.x; by += v0.y; bz += v0.z; bw += v0.w;
    cx += v1.x; cy += v1.y; cz += v1.z; cw += v1.w;
  }
  if (cc < c) { const float4 v0 = p4[(size_t)cc * 16]; bx += v0.x; by += v0.y; bz += v0.z; bw += v0.w; }
  float a0 = bx + cx, a1 = by + cy, a2 = bz + cz, a3 = bw + cw;
  __syncthreads();   // sm_g/sm_tv ready

  const bf16* wp = w + ((size_t)(b * Tt + c * CHL)) * Dm + h * HD + l * 4;
  const float tv = sm_tv[h];
#pragma unroll 8
  for (int i = 0; i < CHL; i++) {
    const ushort4 v = *(const ushort4*)(wp + (size_t)i * Dm);
    const float f0 = b2f(v.x), f1 = b2f(v.y), f2 = b2f(v.z), f3 = b2f(v.w);
    const float s0 = f0 * f0, s1 = f1 * f1, s2 = f2 * f2, s3 = f3 * f3;
    a0 += s0; a1 += s1; a2 += s2; a3 += s3;
    float val = s0 * frcp(fmaxf(a0, 1e-12f)) + s1 * frcp(fmaxf(a1, 1e-12f))
              + s2 * frcp(fmaxf(a2, 1e-12f)) + s3 * frcp(fmaxf(a3, 1e-12f));
    val += __shfl_xor(val, 1, 64);
    val += __shfl_xor(val, 2, 64);
    val += __shfl_xor(val, 4, 64);
    val += __shfl_xor(val, 8, 64);
    if (l == 0) sm_t[i][h] = tv * val;
  }
  __syncthreads();

  if (tid < CHL) {
    const int t = tid;
    const float pen = penalty[(size_t)b * Tt + c * CHL + t];
    float sc[NHh];
    float mx = -1e30f;
#pragma unroll
    for (int hh = 0; hh < NHh; hh++) {
      sc[hh] = sm_t[t][hh] - sm_g[hh] * pen;
      mx = fmaxf(mx, sc[hh]);
    }
    float sum = 0.f;
#pragma unroll
    for (int hh = 0; hh < NHh; hh++) { const float e = __expf(sc[hh] - mx); sc[hh] = e; sum += e; }
    const float inv = 1.f / sum;
#pragma unroll
    for (int hh = 0; hh < NHh; hh++) sm_a[t][hh] = sc[hh] * inv;
  }
  __syncthreads();

#pragma unroll
  for (int k2 = 0; k2 < CHL / 16; k2++) {
    const int t = k2 * 16 + l;
    alpha_f[((size_t)(b * NHh + h)) * Tt + c * CHL + t] = sm_a[t][h];
  }

  float d0 = 0.f, d1 = 0.f, d2 = 0.f, d3 = 0.f, sa = 0.f;
#pragma unroll 8
  for (int i = 0; i < CHL; i++) {
    const float a = sm_a[i][h];
    const ushort4 v = *(const ushort4*)(wp + (size_t)i * Dm);
    const float f0 = b2f(v.x), f1 = b2f(v.y), f2 = b2f(v.z), f3 = b2f(v.w);
    d0 += f0 * f0 * a; d1 += f1 * f1 * a; d2 += f2 * f2 * a; d3 += f3 * f3 * a;
    sa += a;
  }
  float4 o; o.x = d0; o.y = d1; o.z = d2; o.w = d3;
  *(float4*)&S2[(((size_t)(b * NHh + h) * NCH) + c) * HD + l * 4] = o;
  if (l == 0) SA[(size_t)(b * NHh + h) * NCH + c] = sa;
}

// y'[b,t,h*64+d] = -w * alpha * min(1/(1+dots), 1e4), bf16 (4 d/lane).
// S2/SA are RAW chunk sums; inline exclusive prefix over chunks < c per thread.
__global__ __launch_bounds__(64) void y_phase3(const bf16* __restrict__ w,
                                               const float* __restrict__ alpha_f,
                                               const float* __restrict__ S2,
                                               const float* __restrict__ SA,
                                               bf16* __restrict__ yprime) {
  const int g = threadIdx.x >> 4, l = threadIdx.x & 15;
  const int c = blockIdx.x * 4 + g, h = blockIdx.y, b = blockIdx.z;

  // inline exclusive prefix of S2 (vec) and SA (scalar) over chunks < c
  const float4* p4 = (const float4*)(S2 + (((size_t)(b * NHh + h) * NCH)) * HD + l * 4);
  const float* sap = SA + (size_t)(b * NHh + h) * NCH;
  float bx = 0.f, by = 0.f, bz = 0.f, bw = 0.f;
  float cx = 0.f, cy = 0.f, cz = 0.f, cw = 0.f;
  float sa0 = 0.f, sa1 = 0.f;
  int cc = 0;
  for (; cc + 2 <= c; cc += 2) {
    const float4 v0 = p4[(size_t)cc * 16];
    const float4 v1 = p4[(size_t)(cc + 1) * 16];
    bx += v0.x; by += v0.y; bz += v0.z; bw += v0.w;
    cx += v1.x; cy += v1.y; cz += v1.z; cw += v1.w;
    sa0 += sap[cc]; sa1 += sap[cc + 1];
  }
  if (cc < c) {
    const float4 v0 = p4[(size_t)cc * 16];
    bx += v0.x; by += v0.y; bz += v0.z; bw += v0.w;
    sa0 += sap[cc];
  }
  float a0 = bx + cx, a1 = by + cy, a2 = bz + cz, a3 = bw + cw;
  float acca = sa0 + sa1;

  const bf16* wp = w + ((size_t)(b * Tt + c * CHL)) * Dm + h * HD + l * 4;
  const float* ap = alpha_f + (size_t)(b * NHh + h) * Tt + c * CHL;
  bf16* yp = yprime + ((size_t)(b * Tt + c * CHL)) * Dm + h * HD + l * 4;
#pragma unroll 8
  for (int i = 0; i < CHL; i++) {
    const float a = ap[i];
    const ushort4 v = *(const ushort4*)(wp + (size_t)i * Dm);
    const float f0 = b2f(v.x), f1 = b2f(v.y), f2 = b2f(v.z), f3 = b2f(v.w);
    a0 += f0 * f0 * a; a1 += f1 * f1 * a; a2 += f2 * f2 * a; a3 += f3 * f3 * a;
    acca += a;
    const float rinv = frcp(acca + 1e-8f);
    const float at0 = fminf(frcp(1.f + a0 * rinv), 10000.f);
    const float at1 = fminf(frcp(1.f + a1 * rinv), 10000.f);
    const float at2 = fminf(frcp(1.f + a2 * rinv), 10000.f);
    const float at3 = fminf(frcp(1.f + a3 * rinv), 10000.f);
    ushort4 o;
    o.x = __bfloat16_as_ushort(__float2bfloat16(-f0 * a * at0));
    o.y = __bfloat16_as_ushort(__float2bfloat16(-f1 * a * at1));
    o.z = __bfloat16_as_ushort(__float2bfloat16(-f2 * a * at2));
    o.w = __bfloat16_as_ushort(__float2bfloat16(-f3 * a * at3));
    *(ushort4*)(yp + (size_t)i * Dm) = o;
  }
}

extern "C" void kernel_launch(void* const* d_in, const int* in_sizes, int n_in,
                              void* d_out, int out_size, void* d_ws, size_t ws_size,
                              hipStream_t stream) {
  const float* x     = (const float*)d_in[0];
  const float* phi   = (const float*)d_in[1];
  const float* Wattn = (const float*)d_in[2];
  const float* Wproj = (const float*)d_in[3];
  const float* gamma = (const float*)d_in[4];
  const float* temp  = (const float*)d_in[5];

  float* y_out    = (float*)d_out;                          // (B,T,D) fp32
  float* alpha_f  = y_out + (size_t)Bb * Tt * Dm;           // (B,NH,T) fp32

  char* ws = (char*)d_ws;
  bf16*  x_bf   = (bf16*)ws;  ws += (size_t)Bb * Tt * Dm * 2;         // 32 MB
  bf16*  Wa_bf  = (bf16*)ws;  ws += (size_t)Dm * Dm * 2;              // 2 MB
  bf16*  Wp_bf  = (bf16*)ws;  ws += (size_t)Dm * Dm * 2;              // 2 MB
  bf16*  w_bf   = (bf16*)ws;  ws += (size_t)Bb * Tt * Dm * 2;         // 32 MB
  float* pen    = (float*)ws; ws += (size_t)Bb * Tt * 4;              // 64 KB
  float* S1     = (float*)ws; ws += (size_t)Bb * NHh * NCH * HD * 4;  // 2 MB (raw)
  float* S2     = (float*)ws; ws += (size_t)Bb * NHh * NCH * HD * 4;  // 2 MB (raw)
  float* SA     = (float*)ws; ws += (size_t)Bb * NHh * NCH * 4;       // 32 KB (raw)
  bf16*  yprime = x_bf;  // alias: x_bf is dead after GEMM1

  static int attr_done = 0;
  if (!attr_done) {
    hipFuncSetAttribute((const void*)gemm256<true, true>,
                        hipFuncAttributeMaxDynamicSharedMemorySize, 131072);
    hipFuncSetAttribute((const void*)gemm256<false, false>,
                        hipFuncAttributeMaxDynamicSharedMemorySize, 131072);
    attr_done = 1;
  }

  const int M = Bb * Tt, N = Dm, K = Dm;
  dim3 gg((M / BM) * (N / BN)), gb(512);

  prep<<<dim3(1540), dim3(256), 0, stream>>>(x, Wattn, Wproj, phi, x_bf, Wa_bf, Wp_bf, pen);
  gemm256<true, true><<<gg, gb, 131072, stream>>>(x_bf, Wa_bf, (void*)w_bf, S1, M, N, K);
  mid_fused<<<dim3(NCH, Bb), dim3(256), 0, stream>>>(w_bf, S1, temp, gamma, pen,
                                                     alpha_f, S2, SA);
  y_phase3<<<dim3(NCH / 4, NHh, Bb), dim3(64), 0, stream>>>(w_bf, alpha_f, S2, SA, yprime);
  gemm256<false, false><<<gg, gb, 131072, stream>>>(yprime, Wp_bf, (void*)y_out, nullptr, M, N, K);
}

// Round 6
// 253.688 us; speedup vs baseline: 1.0635x; 1.0577x over previous
//
#include <hip/hip_runtime.h>
#include <hip/hip_bf16.h>
#include <stdint.h>

// Problem constants (B,T,D,NH from reference)
#define NHh 16
#define Dm  1024
#define HD  64          // head dim = D/NH
#define Bb  4
#define Tt  4096
#define NCH 128         // chunks along T for the two-pass scans
#define CHL 32          // chunk length (NCH*CHL == Tt)

// 256x256 GEMM tile geometry
#define BM 256
#define BN 256
#define BK 64
#define NKT (Dm / BK)   // 16 K-tiles

using bf16 = __hip_bfloat16;
typedef __attribute__((ext_vector_type(8))) short short8;   // 8 bf16 in 4 VGPRs (MFMA A/B frag)
typedef __attribute__((ext_vector_type(4))) float f32x4;    // MFMA C/D frag

__device__ __forceinline__ float bf2f(bf16 v) { return __bfloat162float(v); }

// bf16 bits -> f32 (exact): bf16 is the high 16 bits of f32
__device__ __forceinline__ float b2f(unsigned short u) {
  union { unsigned int i; float f; } x; x.i = ((unsigned int)u) << 16; return x.f;
}

// fast reciprocal via v_rcp_f32 (~1 ulp; inputs are bf16-derived, tolerance is 1e-2)
__device__ __forceinline__ float frcp(float x) {
  float r; asm("v_rcp_f32 %0, %1" : "=v"(r) : "v"(x)); return r;
}

// async global->LDS, 16B per lane. LDS dest is wave-uniform base + lane*16.
__device__ __forceinline__ void gld_lds16(const void* g, void* l) {
  __builtin_amdgcn_global_load_lds(
      (const __attribute__((address_space(1))) unsigned int*)g,
      (__attribute__((address_space(3))) unsigned int*)l, 16, 0, 0);
}

// ============== 256x256 GEMM, counted-vmcnt 2-phase pipeline (round-2 best) ==
template <bool OUT_BF16, bool WRITE_S1>
__global__ __launch_bounds__(512, 2) void gemm256(const bf16* __restrict__ A,
                                                  const bf16* __restrict__ W,
                                                  void* __restrict__ Cout,
                                                  float* __restrict__ S1,
                                                  int M, int N, int K) {
  extern __shared__ char smem[];   // 131072 B: [buf][A 32K | B 32K]
  const int tid  = threadIdx.x;
  const int lane = tid & 63;
  const int wave = tid >> 6;       // 0..7
  // T1 XCD swizzle: 256 blocks = 8 XCDs x 32; consecutive swz share the A-panel
  const int bid = blockIdx.x;
  const int swz = (bid & 7) * 32 + (bid >> 3);
  const int bn = (swz & 3) * BN;          // N/BN = 4
  const int bm = (swz >> 2) * BM;
  const int wm = (wave >> 1) * 64;        // 4 M bands of 64 rows
  const int wn = (wave & 1) * 128;        // 2 N halves of 128 cols
  const int quad = lane >> 4;
  const int l16  = lane & 15;

  // staging source (per lane, per slab n): inverse-swizzled global address
  const int srow = wave * 8 + (lane >> 3);               // + n*64
  const int scol = (((lane & 7) ^ (lane >> 3)) << 3);    // elements

  const bf16* Abase = A + (size_t)(bm + srow) * K + scol;
  const bf16* Wbase = W + (size_t)(bn + srow) * K + scol;

  f32x4 acc[4][8] = {};

#define SLAB_A(buf, n) (smem + (buf) * 65536 + (n) * 8192 + wave * 1024)
#define SLAB_B(buf, n) (smem + (buf) * 65536 + 32768 + (n) * 8192 + wave * 1024)
#define STAGE_A(buf, n, k0) gld_lds16(Abase + (size_t)(n) * 64 * K + (k0), SLAB_A(buf, n))
#define STAGE_B(buf, n, k0) gld_lds16(Wbase + (size_t)(n) * 64 * K + (k0), SLAB_B(buf, n))
#define LD_FRAG(base, r, s) (*(const short8*)((base) + (size_t)(r) * 128 + ((((s) ^ ((r) & 7))) << 4)))

  // prologue: stage tile 0 fully into buf 0
  STAGE_A(0, 0, 0); STAGE_A(0, 1, 0); STAGE_A(0, 2, 0); STAGE_A(0, 3, 0);
  STAGE_B(0, 0, 0); STAGE_B(0, 1, 0); STAGE_B(0, 2, 0); STAGE_B(0, 3, 0);
  asm volatile("s_waitcnt vmcnt(0)" ::: "memory");
  __builtin_amdgcn_s_barrier();
  __builtin_amdgcn_sched_barrier(0);

  short8 af[4][2], bfv[4][2];
  for (int t = 0; t < NKT; t++) {
    const int buf = t & 1;
    const char* aL = smem + buf * 65536;
    const char* bL = aL + 32768;
    const int k0n = (t + 1) * BK;
    const bool pf = (t + 1 < NKT);

    // ---- P1: stage 6 slabs (t+1), read A-all + B lower-halves, MFMA nj 0-3
    if (pf) {
      STAGE_A(buf ^ 1, 0, k0n); STAGE_A(buf ^ 1, 1, k0n);
      STAGE_A(buf ^ 1, 2, k0n); STAGE_A(buf ^ 1, 3, k0n);
      STAGE_B(buf ^ 1, 0, k0n); STAGE_B(buf ^ 1, 2, k0n);
    }
#pragma unroll
    for (int mi = 0; mi < 4; mi++) {
      const int r = wm + mi * 16 + l16;
      af[mi][0] = LD_FRAG(aL, r, quad);
      af[mi][1] = LD_FRAG(aL, r, quad + 4);
    }
#pragma unroll
    for (int nj = 0; nj < 4; nj++) {
      const int r = wn + nj * 16 + l16;
      bfv[nj][0] = LD_FRAG(bL, r, quad);
      bfv[nj][1] = LD_FRAG(bL, r, quad + 4);
    }
    __builtin_amdgcn_s_setprio(1);
#pragma unroll
    for (int mi = 0; mi < 4; mi++)
#pragma unroll
      for (int nj = 0; nj < 4; nj++) {
        acc[mi][nj] = __builtin_amdgcn_mfma_f32_16x16x32_bf16(af[mi][0], bfv[nj][0], acc[mi][nj], 0, 0, 0);
        acc[mi][nj] = __builtin_amdgcn_mfma_f32_16x16x32_bf16(af[mi][1], bfv[nj][1], acc[mi][nj], 0, 0, 0);
      }
    __builtin_amdgcn_s_setprio(0);
    if (pf) { asm volatile("s_waitcnt vmcnt(6)" ::: "memory"); }
    else    { asm volatile("s_waitcnt vmcnt(0)" ::: "memory"); }
    __builtin_amdgcn_s_barrier();
    __builtin_amdgcn_sched_barrier(0);

    // ---- P2: stage 2 slabs (t+1), read B upper-halves, MFMA nj 4-7
    if (pf) { STAGE_B(buf ^ 1, 1, k0n); STAGE_B(buf ^ 1, 3, k0n); }
#pragma unroll
    for (int nj = 0; nj < 4; nj++) {
      const int r = wn + 64 + nj * 16 + l16;
      bfv[nj][0] = LD_FRAG(bL, r, quad);
      bfv[nj][1] = LD_FRAG(bL, r, quad + 4);
    }
    __builtin_amdgcn_s_setprio(1);
#pragma unroll
    for (int mi = 0; mi < 4; mi++)
#pragma unroll
      for (int nj = 0; nj < 4; nj++) {
        acc[mi][nj + 4] = __builtin_amdgcn_mfma_f32_16x16x32_bf16(af[mi][0], bfv[nj][0], acc[mi][nj + 4], 0, 0, 0);
        acc[mi][nj + 4] = __builtin_amdgcn_mfma_f32_16x16x32_bf16(af[mi][1], bfv[nj][1], acc[mi][nj + 4], 0, 0, 0);
      }
    __builtin_amdgcn_s_setprio(0);
    asm volatile("s_waitcnt vmcnt(2)" ::: "memory");
    __builtin_amdgcn_s_barrier();
    __builtin_amdgcn_sched_barrier(0);
  }

  // C/D layout (HW-verified): col = lane&15, row = (lane>>4)*4 + reg
#pragma unroll
  for (int nj = 0; nj < 8; nj++) {
    const int col = bn + wn + nj * 16 + l16;
    if constexpr (OUT_BF16) {
      float ss0 = 0.f, ss1 = 0.f;   // two 32-row chunks of this wave's 64-row band
#pragma unroll
      for (int mi = 0; mi < 4; mi++) {
        float csum = 0.f;
#pragma unroll
        for (int r = 0; r < 4; r++) {
          const int row = bm + wm + mi * 16 + quad * 4 + r;
          const bf16 hv = __float2bfloat16(acc[mi][nj][r]);
          ((bf16*)Cout)[(size_t)row * N + col] = hv;
          if constexpr (WRITE_S1) { const float fv = bf2f(hv); csum += fv * fv; }
        }
        if constexpr (WRITE_S1) { if (mi < 2) ss0 += csum; else ss1 += csum; }
      }
      if constexpr (WRITE_S1) {
        ss0 += __shfl_xor(ss0, 16, 64); ss0 += __shfl_xor(ss0, 32, 64);
        ss1 += __shfl_xor(ss1, 16, 64); ss1 += __shfl_xor(ss1, 32, 64);
        if (quad == 0) {
          const int h = col >> 6, d = col & 63;
          const int r0 = bm + wm;                    // first row of this wave's band
          const int b  = r0 >> 12;                   // / Tt
          const int c0 = (r0 & (Tt - 1)) >> 5;       // / CHL (=32)
          float* s1p = S1 + (((size_t)(b * NHh + h) * NCH) + c0) * HD + d;
          s1p[0]  = ss0;
          s1p[HD] = ss1;
        }
      }
    } else {
#pragma unroll
      for (int mi = 0; mi < 4; mi++)
#pragma unroll
        for (int r = 0; r < 4; r++) {
          const int row = bm + wm + mi * 16 + quad * 4 + r;
          ((float*)Cout)[(size_t)row * N + col] = acc[mi][nj][r];
        }
    }
  }
#undef SLAB_A
#undef SLAB_B
#undef STAGE_A
#undef STAGE_B
#undef LD_FRAG
}

// ===== prep: fused {cast x, cast W_attn, cast W_proj, phi->penalty} ==========
__global__ __launch_bounds__(256) void prep(const float* __restrict__ x,
                                            const float* __restrict__ Wa,
                                            const float* __restrict__ Wp,
                                            const float* __restrict__ phi,
                                            bf16* __restrict__ x_bf,
                                            bf16* __restrict__ Wa_bf,
                                            bf16* __restrict__ Wp_bf,
                                            float* __restrict__ penalty) {
  const int bid = blockIdx.x;
  if (bid < 1536) {
    const float* in;
    bf16* out;
    int n, nblk, b0;
    if (bid < 1024)      { in = x;  out = x_bf;  n = Bb * Tt * Dm; nblk = 1024; b0 = 0; }
    else if (bid < 1280) { in = Wa; out = Wa_bf; n = Dm * Dm;      nblk = 256;  b0 = 1024; }
    else                 { in = Wp; out = Wp_bf; n = Dm * Dm;      nblk = 256;  b0 = 1280; }
    const int stride = nblk * 256;
    for (int i = (bid - b0) * 256 + threadIdx.x; i * 4 < n; i += stride) {
      const float4 v = *(const float4*)(in + (size_t)i * 4);
      ushort4 o;
      o.x = __bfloat16_as_ushort(__float2bfloat16(v.x));
      o.y = __bfloat16_as_ushort(__float2bfloat16(v.y));
      o.z = __bfloat16_as_ushort(__float2bfloat16(v.z));
      o.w = __bfloat16_as_ushort(__float2bfloat16(v.w));
      *(ushort4*)(out + (size_t)i * 4) = o;
    }
  } else {
    const int b = bid - 1536;
    const int tid = threadIdx.x;            // 256
    const int lane = tid & 63, wid = tid >> 6;
    __shared__ float wsum[4];
    __shared__ float carry_s;
    if (tid == 0) carry_s = 0.f;
    __syncthreads();
    for (int r = 0; r < Tt / 256; r++) {
      const int t = r * 256 + tid;
      const float v = phi[b * Tt + t];
      float incl = v;
#pragma unroll
      for (int off = 1; off < 64; off <<= 1) {
        float nn = __shfl_up(incl, off, 64);
        if (lane >= off) incl += nn;
      }
      if (lane == 63) wsum[wid] = incl;
      __syncthreads();
      float woff = carry_s;
      for (int wpre = 0; wpre < wid; wpre++) woff += wsum[wpre];
      const float csum = woff + incl;
      const float mean = csum / (float)(t + 1);
      const float dphi = v - mean;
      penalty[b * Tt + t] = dphi * dphi;
      __syncthreads();
      if (tid == 0) carry_s += wsum[0] + wsum[1] + wsum[2] + wsum[3];
      __syncthreads();
    }
  }
}

// ===== fused middle: inline S1 prefix -> tssa -> softmax(heads) -> dots sums =
__global__ __launch_bounds__(256) void mid_fused(const bf16* __restrict__ w,
                                                 const float* __restrict__ S1,
                                                 const float* __restrict__ temp,
                                                 const float* __restrict__ gamma,
                                                 const float* __restrict__ penalty,
                                                 float* __restrict__ alpha_f,
                                                 float* __restrict__ S2,
                                                 float* __restrict__ SA) {
  const int c = blockIdx.x, b = blockIdx.y;
  const int tid = threadIdx.x, h = tid >> 4, l = tid & 15;
  __shared__ float sm_t[CHL][NHh + 1];
  __shared__ float sm_a[CHL][NHh + 1];
  __shared__ float sm_g[NHh], sm_tv[NHh];
  if (tid < NHh) { sm_g[tid] = gamma[tid]; sm_tv[tid] = temp[tid]; }

  // inline exclusive prefix of S1 over chunks < c, 4-deep ILP
  const float4* p4 = (const float4*)(S1 + (((size_t)(b * NHh + h) * NCH)) * HD + l * 4);
  float4 s0 = {0,0,0,0}, s1v = {0,0,0,0}, s2v = {0,0,0,0}, s3v = {0,0,0,0};
  int cc = 0;
  for (; cc + 4 <= c; cc += 4) {
    const float4 v0 = p4[(size_t)cc * 16];
    const float4 v1 = p4[(size_t)(cc + 1) * 16];
    const float4 v2 = p4[(size_t)(cc + 2) * 16];
    const float4 v3 = p4[(size_t)(cc + 3) * 16];
    s0.x += v0.x; s0.y += v0.y; s0.z += v0.z; s0.w += v0.w;
    s1v.x += v1.x; s1v.y += v1.y; s1v.z += v1.z; s1v.w += v1.w;
    s2v.x += v2.x; s2v.y += v2.y; s2v.z += v2.z; s2v.w += v2.w;
    s3v.x += v3.x; s3v.y += v3.y; s3v.z += v3.z; s3v.w += v3.w;
  }
  for (; cc < c; cc++) {
    const float4 v0 = p4[(size_t)cc * 16];
    s0.x += v0.x; s0.y += v0.y; s0.z += v0.z; s0.w += v0.w;
  }
  float a0 = s0.x + s1v.x + s2v.x + s3v.x;
  float a1 = s0.y + s1v.y + s2v.y + s3v.y;
  float a2 = s0.z + s1v.z + s2v.z + s3v.z;
  float a3 = s0.w + s1v.w + s2v.w + s3v.w;
  __syncthreads();   // sm_g/sm_tv ready

  const bf16* wp = w + ((size_t)(b * Tt + c * CHL)) * Dm + h * HD + l * 4;
  const float tv = sm_tv[h];
#pragma unroll 8
  for (int i = 0; i < CHL; i++) {
    const ushort4 v = *(const ushort4*)(wp + (size_t)i * Dm);
    const float f0 = b2f(v.x), f1 = b2f(v.y), f2 = b2f(v.z), f3 = b2f(v.w);
    const float q0 = f0 * f0, q1 = f1 * f1, q2 = f2 * f2, q3 = f3 * f3;
    a0 += q0; a1 += q1; a2 += q2; a3 += q3;
    float val = q0 * frcp(fmaxf(a0, 1e-12f)) + q1 * frcp(fmaxf(a1, 1e-12f))
              + q2 * frcp(fmaxf(a2, 1e-12f)) + q3 * frcp(fmaxf(a3, 1e-12f));
    val += __shfl_xor(val, 1, 64);
    val += __shfl_xor(val, 2, 64);
    val += __shfl_xor(val, 4, 64);
    val += __shfl_xor(val, 8, 64);
    if (l == 0) sm_t[i][h] = tv * val;
  }
  __syncthreads();

  if (tid < CHL) {
    const int t = tid;
    const float pen = penalty[(size_t)b * Tt + c * CHL + t];
    float sc[NHh];
    float mx = -1e30f;
#pragma unroll
    for (int hh = 0; hh < NHh; hh++) {
      sc[hh] = sm_t[t][hh] - sm_g[hh] * pen;
      mx = fmaxf(mx, sc[hh]);
    }
    float sum = 0.f;
#pragma unroll
    for (int hh = 0; hh < NHh; hh++) { const float e = __expf(sc[hh] - mx); sc[hh] = e; sum += e; }
    const float inv = 1.f / sum;
#pragma unroll
    for (int hh = 0; hh < NHh; hh++) sm_a[t][hh] = sc[hh] * inv;
  }
  __syncthreads();

#pragma unroll
  for (int k2 = 0; k2 < CHL / 16; k2++) {
    const int t = k2 * 16 + l;
    alpha_f[((size_t)(b * NHh + h)) * Tt + c * CHL + t] = sm_a[t][h];
  }

  float d0 = 0.f, d1 = 0.f, d2 = 0.f, d3 = 0.f, sa = 0.f;
#pragma unroll 8
  for (int i = 0; i < CHL; i++) {
    const float a = sm_a[i][h];
    const ushort4 v = *(const ushort4*)(wp + (size_t)i * Dm);
    const float f0 = b2f(v.x), f1 = b2f(v.y), f2 = b2f(v.z), f3 = b2f(v.w);
    d0 += f0 * f0 * a; d1 += f1 * f1 * a; d2 += f2 * f2 * a; d3 += f3 * f3 * a;
    sa += a;
  }
  float4 o; o.x = d0; o.y = d1; o.z = d2; o.w = d3;
  *(float4*)&S2[(((size_t)(b * NHh + h) * NCH) + c) * HD + l * 4] = o;
  if (l == 0) SA[(size_t)(b * NHh + h) * NCH + c] = sa;
}

// ===== y': full-row blocks. grid (NCH, Bb), 256 threads = 16 heads x 16 lanes.
// Each wave reads/writes 512 B contiguous; block covers full 2 KB rows of
// w/yprime (vs previous 128 B/row slices).  SA prefix: lanes split chunks +
// shfl-reduce.  S2 prefix: per-thread own columns, 4-deep ILP.
__global__ __launch_bounds__(256) void y_phase3(const bf16* __restrict__ w,
                                                const float* __restrict__ alpha_f,
                                                const float* __restrict__ S2,
                                                const float* __restrict__ SA,
                                                bf16* __restrict__ yprime) {
  const int c = blockIdx.x, b = blockIdx.y;
  const int tid = threadIdx.x, h = tid >> 4, l = tid & 15;

  // SA exclusive prefix over chunks < c: lane l sums cc = l, l+16, ... then 4-step reduce
  const float* sap = SA + (size_t)(b * NHh + h) * NCH;
  float sa_part = 0.f;
  for (int cc = l; cc < c; cc += 16) sa_part += sap[cc];
  sa_part += __shfl_xor(sa_part, 1, 64);
  sa_part += __shfl_xor(sa_part, 2, 64);
  sa_part += __shfl_xor(sa_part, 4, 64);
  sa_part += __shfl_xor(sa_part, 8, 64);
  float acca = sa_part;   // uniform within the 16-lane group

  // S2 exclusive prefix over chunks < c (own 4 columns), 4-deep ILP
  const float4* p4 = (const float4*)(S2 + (((size_t)(b * NHh + h) * NCH)) * HD + l * 4);
  float4 s0 = {0,0,0,0}, s1v = {0,0,0,0}, s2v = {0,0,0,0}, s3v = {0,0,0,0};
  int cc = 0;
  for (; cc + 4 <= c; cc += 4) {
    const float4 v0 = p4[(size_t)cc * 16];
    const float4 v1 = p4[(size_t)(cc + 1) * 16];
    const float4 v2 = p4[(size_t)(cc + 2) * 16];
    const float4 v3 = p4[(size_t)(cc + 3) * 16];
    s0.x += v0.x; s0.y += v0.y; s0.z += v0.z; s0.w += v0.w;
    s1v.x += v1.x; s1v.y += v1.y; s1v.z += v1.z; s1v.w += v1.w;
    s2v.x += v2.x; s2v.y += v2.y; s2v.z += v2.z; s2v.w += v2.w;
    s3v.x += v3.x; s3v.y += v3.y; s3v.z += v3.z; s3v.w += v3.w;
  }
  for (; cc < c; cc++) {
    const float4 v0 = p4[(size_t)cc * 16];
    s0.x += v0.x; s0.y += v0.y; s0.z += v0.z; s0.w += v0.w;
  }
  float a0 = s0.x + s1v.x + s2v.x + s3v.x;
  float a1 = s0.y + s1v.y + s2v.y + s3v.y;
  float a2 = s0.z + s1v.z + s2v.z + s3v.z;
  float a3 = s0.w + s1v.w + s2v.w + s3v.w;

  const bf16* wp = w + ((size_t)(b * Tt + c * CHL)) * Dm + h * HD + l * 4;
  const float* ap = alpha_f + (size_t)(b * NHh + h) * Tt + c * CHL;
  bf16* yp = yprime + ((size_t)(b * Tt + c * CHL)) * Dm + h * HD + l * 4;
#pragma unroll 8
  for (int i = 0; i < CHL; i++) {
    const float a = ap[i];
    const ushort4 v = *(const ushort4*)(wp + (size_t)i * Dm);
    const float f0 = b2f(v.x), f1 = b2f(v.y), f2 = b2f(v.z), f3 = b2f(v.w);
    a0 += f0 * f0 * a; a1 += f1 * f1 * a; a2 += f2 * f2 * a; a3 += f3 * f3 * a;
    acca += a;
    const float rinv = frcp(acca + 1e-8f);
    const float at0 = fminf(frcp(1.f + a0 * rinv), 10000.f);
    const float at1 = fminf(frcp(1.f + a1 * rinv), 10000.f);
    const float at2 = fminf(frcp(1.f + a2 * rinv), 10000.f);
    const float at3 = fminf(frcp(1.f + a3 * rinv), 10000.f);
    ushort4 o;
    o.x = __bfloat16_as_ushort(__float2bfloat16(-f0 * a * at0));
    o.y = __bfloat16_as_ushort(__float2bfloat16(-f1 * a * at1));
    o.z = __bfloat16_as_ushort(__float2bfloat16(-f2 * a * at2));
    o.w = __bfloat16_as_ushort(__float2bfloat16(-f3 * a * at3));
    *(ushort4*)(yp + (size_t)i * Dm) = o;
  }
}

extern "C" void kernel_launch(void* const* d_in, const int* in_sizes, int n_in,
                              void* d_out, int out_size, void* d_ws, size_t ws_size,
                              hipStream_t stream) {
  const float* x     = (const float*)d_in[0];
  const float* phi   = (const float*)d_in[1];
  const float* Wattn = (const float*)d_in[2];
  const float* Wproj = (const float*)d_in[3];
  const float* gamma = (const float*)d_in[4];
  const float* temp  = (const float*)d_in[5];

  float* y_out    = (float*)d_out;                          // (B,T,D) fp32
  float* alpha_f  = y_out + (size_t)Bb * Tt * Dm;           // (B,NH,T) fp32

  char* ws = (char*)d_ws;
  bf16*  x_bf   = (bf16*)ws;  ws += (size_t)Bb * Tt * Dm * 2;         // 32 MB
  bf16*  Wa_bf  = (bf16*)ws;  ws += (size_t)Dm * Dm * 2;              // 2 MB
  bf16*  Wp_bf  = (bf16*)ws;  ws += (size_t)Dm * Dm * 2;              // 2 MB
  bf16*  w_bf   = (bf16*)ws;  ws += (size_t)Bb * Tt * Dm * 2;         // 32 MB
  float* pen    = (float*)ws; ws += (size_t)Bb * Tt * 4;              // 64 KB
  float* S1     = (float*)ws; ws += (size_t)Bb * NHh * NCH * HD * 4;  // 2 MB (raw)
  float* S2     = (float*)ws; ws += (size_t)Bb * NHh * NCH * HD * 4;  // 2 MB (raw)
  float* SA     = (float*)ws; ws += (size_t)Bb * NHh * NCH * 4;       // 32 KB (raw)
  bf16*  yprime = x_bf;  // alias: x_bf is dead after GEMM1

  static int attr_done = 0;
  if (!attr_done) {
    hipFuncSetAttribute((const void*)gemm256<true, true>,
                        hipFuncAttributeMaxDynamicSharedMemorySize, 131072);
    hipFuncSetAttribute((const void*)gemm256<false, false>,
                        hipFuncAttributeMaxDynamicSharedMemorySize, 131072);
    attr_done = 1;
  }

  const int M = Bb * Tt, N = Dm, K = Dm;
  dim3 gg((M / BM) * (N / BN)), gb(512);

  prep<<<dim3(1540), dim3(256), 0, stream>>>(x, Wattn, Wproj, phi, x_bf, Wa_bf, Wp_bf, pen);
  gemm256<true, true><<<gg, gb, 131072, stream>>>(x_bf, Wa_bf, (void*)w_bf, S1, M, N, K);
  mid_fused<<<dim3(NCH, Bb), dim3(256), 0, stream>>>(w_bf, S1, temp, gamma, pen,
                                                     alpha_f, S2, SA);
  y_phase3<<<dim3(NCH, Bb), dim3(256), 0, stream>>>(w_bf, alpha_f, S2, SA, yprime);
  gemm256<false, false><<<gg, gb, 131072, stream>>>(yprime, Wp_bf, (void*)y_out, nullptr, M, N, K);
}